// Round 13
// baseline (164.575 us; speedup 1.0000x reference)
//
#include <hip/hip_runtime.h>
#include <stdint.h>

#define N_IN  128
#define N_H   256
#define N_OUT 64
#define CHK   2048   // edges per scatter block
#define CAP   6144   // fixed bucket capacity (mean 4096, sigma ~64 -> 32-sigma margin)

typedef __attribute__((ext_vector_type(8))) __bf16 bf16x8;
typedef __attribute__((ext_vector_type(4))) float f32x4;

// ---------------- Threefry-2x32 (JAX-compatible) ----------------
__device__ __forceinline__ void tf4(uint32_t& x0, uint32_t& x1,
                                    const int r0, const int r1, const int r2, const int r3) {
  x0 += x1; x1 = (x1 << r0) | (x1 >> (32 - r0)); x1 ^= x0;
  x0 += x1; x1 = (x1 << r1) | (x1 >> (32 - r1)); x1 ^= x0;
  x0 += x1; x1 = (x1 << r2) | (x1 >> (32 - r2)); x1 ^= x0;
  x0 += x1; x1 = (x1 << r3) | (x1 >> (32 - r3)); x1 ^= x0;
}

__device__ __forceinline__ uint2 threefry2x32(uint32_t k0, uint32_t k1, uint32_t x0, uint32_t x1) {
  const uint32_t k2 = k0 ^ k1 ^ 0x1BD11BDAu;
  x0 += k0; x1 += k1;
  tf4(x0, x1, 13, 15, 26, 6);   x0 += k1; x1 += k2 + 1u;
  tf4(x0, x1, 17, 29, 16, 24);  x0 += k2; x1 += k0 + 2u;
  tf4(x0, x1, 13, 15, 26, 6);   x0 += k0; x1 += k1 + 3u;
  tf4(x0, x1, 17, 29, 16, 24);  x0 += k1; x1 += k2 + 4u;
  tf4(x0, x1, 13, 15, 26, 6);   x0 += k2; x1 += k0 + 5u;
  return make_uint2(x0, x1);
}

// f32 -> bf16 round-to-nearest-even
__device__ __forceinline__ uint16_t f2bf_rne(float v) {
  uint32_t b = __builtin_bit_cast(uint32_t, v);
  b += 0x7fffu + ((b >> 16) & 1u);
  return (uint16_t)(b >> 16);
}
__device__ __forceinline__ float bflo(uint32_t w) { return __builtin_bit_cast(float, w << 16); }
__device__ __forceinline__ float bfhi(uint32_t w) { return __builtin_bit_cast(float, w & 0xffff0000u); }

// ---------------- W fragment packing body ----------------
__device__ __forceinline__ void packW_body(const float* __restrict__ W,
                                           uint4* __restrict__ WH, uint4* __restrict__ WL,
                                           int Ncols, int nct, int nks, int g) {
  if (g >= nct * nks * 64) return;
  int lane = g & 63;
  int grp = g >> 6;
  int ks = grp % nks, ct = grp / nks;
  int k0 = ks * 32 + (lane >> 4) * 8;
  int col = ct * 16 + (lane & 15);
  uint32_t hb[8], lb[8];
#pragma unroll
  for (int j = 0; j < 8; j++) {
    float w = W[(size_t)(k0 + j) * Ncols + col];
    uint32_t bits = __builtin_bit_cast(uint32_t, w);
    uint32_t hi = bits & 0xffff0000u;
    float lo = w - __builtin_bit_cast(float, hi);
    hb[j] = hi >> 16;
    lb[j] = __builtin_bit_cast(uint32_t, lo) >> 16;
  }
  WH[g] = make_uint4(hb[0] | (hb[1] << 16), hb[2] | (hb[3] << 16),
                     hb[4] | (hb[5] << 16), hb[6] | (hb[7] << 16));
  WL[g] = make_uint4(lb[0] | (lb[1] << 16), lb[2] | (lb[3] << 16),
                     lb[4] | (lb[5] << 16), lb[6] | (lb[7] << 16));
}

// ---------------- k_front: fused [edge scatter | dropout mask | W packs] ----------------
__global__ __launch_bounds__(256) void k_front(
    const int* __restrict__ eidx, int E, int* __restrict__ bktCur, uint2* __restrict__ eb,
    uint16_t* __restrict__ mask, int N,
    const float* __restrict__ W1, uint4* __restrict__ W1H, uint4* __restrict__ W1L,
    const float* __restrict__ W2, uint4* __restrict__ W2H, uint4* __restrict__ W2L,
    int NBE) {
  const int b = blockIdx.x, t = threadIdx.x;
  if (b < NBE) {
    __shared__ int s_nz;
    __shared__ int hist[256];
    __shared__ int base[256];
    if (t == 0) s_nz = 0;
    hist[t] = 0;
    __syncthreads();
    int n = E < 2048 ? E : 2048;
    int nz = 0;
    for (int i = t; i < n; i += 256) nz |= (eidx[2 * i + 1] != 0) ? 1 : 0;
    if (nz) atomicAdd(&s_nz, 1);
    __syncthreads();
    int stride = (s_nz == 0) ? 2 : 1;

    int cb = b * CHK;
    int dc[8], sc[8];
#pragma unroll
    for (int i = 0; i < 8; i++) {
      int e = cb + i * 256 + t;
      if (e < E) {
        dc[i] = eidx[(size_t)(E + e) * stride];
        sc[i] = eidx[(size_t)e * stride];
        atomicAdd(&hist[dc[i] >> 8], 1);
      } else dc[i] = -1;
    }
    __syncthreads();
    int hcnt = hist[t];
    if (hcnt) base[t] = atomicAdd(&bktCur[t], hcnt);
    __syncthreads();
    hist[t] = 0;
    __syncthreads();
#pragma unroll
    for (int i = 0; i < 8; i++) {
      if (dc[i] >= 0) {
        int bk = dc[i] >> 8;
        int r = atomicAdd(&hist[bk], 1);
        eb[(size_t)bk * CAP + base[bk] + r] = make_uint2((unsigned)sc[i], (unsigned)dc[i]);
      }
    }
  } else {
    const int NBM = (N * 16 + 255) >> 8;
    int bb = b - NBE;
    if (bb < NBM) {
      int g = bb * 256 + t;
      if (g >= N * 16) return;
      uint32_t row = (uint32_t)(g >> 4), colb = (uint32_t)(g & 15);
      uint32_t bse = row * 256u + colb;
      uint32_t m = 0;
#pragma unroll
      for (int ct = 0; ct < 16; ct++) {
        uint2 o = threefry2x32(0u, 42u, 0u, bse + (uint32_t)ct * 16u);
        uint32_t bits = o.x ^ o.y;
        m |= ((~bits) >> 31) << ct;
      }
      mask[g] = (uint16_t)m;
    } else if (bb < NBM + 16) {
      packW_body(W1, W1H, W1L, N_H, 16, 4, (bb - NBM) * 256 + t);
    } else {
      packW_body(W2, W2H, W2L, N_OUT, 4, 8, (bb - NBM - 16) * 256 + t);
    }
  }
}

// ---------------- per-bucket CSR build ----------------
__global__ __launch_bounds__(256) void k_bucket_csr(
    const uint2* __restrict__ eb, const int* __restrict__ bktCur,
    int* __restrict__ rowptr, float* __restrict__ norm,
    int* __restrict__ esrc, int N, int E) {
  __shared__ int s[256];
  __shared__ int cnt[256];
  __shared__ int pfx[256];
  __shared__ int cur[256];
  const int b = blockIdx.x, t = threadIdx.x;
  if (b == 0 && t == 0) rowptr[N] = E;
  if (b * 256 >= N) return;
  int xc = bktCur[t];
  s[t] = xc;
  __syncthreads();
  for (int off = 1; off < 256; off <<= 1) {
    int u = (t >= off) ? s[t - off] : 0;
    __syncthreads();
    s[t] += u;
    __syncthreads();
  }
  const int lo = (b > 0) ? s[b - 1] : 0;
  const int ecnt = s[b] - lo;
  const uint2* ebb = eb + (size_t)b * CAP;
  cnt[t] = 0;
  __syncthreads();
  for (int e = t; e < ecnt; e += 256)
    atomicAdd(&cnt[ebb[e].y & 255u], 1);
  __syncthreads();
  int x = cnt[t];
  pfx[t] = x;
  __syncthreads();
  for (int off = 1; off < 256; off <<= 1) {
    int u = (t >= off) ? pfx[t - off] : 0;
    __syncthreads();
    pfx[t] += u;
    __syncthreads();
  }
  int excl = pfx[t] - x;
  int node = b * 256 + t;
  if (node < N) {
    rowptr[node] = lo + excl;
    norm[node] = x > 0 ? rsqrtf((float)x) : 1.0f;
  }
  cur[t] = excl;
  __syncthreads();
  for (int e = t; e < ecnt; e += 256) {
    uint2 r = ebb[e];
    int d = (int)(r.y & 255u);
    int p = atomicAdd(&cur[d], 1);
    esrc[lo + p] = (int)r.x;
  }
}

// ---------------- k_mid: fused [bitonic row sort | hn = bf16(h*norm) plane] ----------------
__global__ __launch_bounds__(256) void k_mid(
    int* __restrict__ esrc, const int* __restrict__ rowptr, int N,
    const float* __restrict__ h, const float* __restrict__ norm,
    uint16_t* __restrict__ hn, int NS) {
  const int b = blockIdx.x, t = threadIdx.x;
  if (b < NS) {
    int node = b * 4 + (t >> 6);
    if (node >= N) return;
    const int lane = t & 63;
    int lo = rowptr[node], hi = rowptr[node + 1], d = hi - lo;
    if (d <= 1) return;
    if (d <= 64) {
      int v = (lane < d) ? esrc[lo + lane] : 0x7fffffff;
#pragma unroll
      for (int k = 2; k <= 64; k <<= 1) {
#pragma unroll
        for (int j = k >> 1; j > 0; j >>= 1) {
          int other = __shfl_xor(v, j);
          bool up = ((lane & k) == 0);
          bool lower = ((lane & j) == 0);
          int mn = min(v, other), mx = max(v, other);
          v = (up == lower) ? mn : mx;
        }
      }
      if (lane < d) esrc[lo + lane] = v;
    } else if (lane == 0) {
      for (int i = lo + 1; i < hi; i++) {
        int v = esrc[i];
        int j = i - 1;
        while (j >= lo && esrc[j] > v) { esrc[j + 1] = esrc[j]; j--; }
        esrc[j + 1] = v;
      }
    }
  } else {
    int g = (b - NS) * 256 + t;
    if (g >= N * 32) return;
    float nr = norm[g >> 5];
    float4 v = *reinterpret_cast<const float4*>(h + (size_t)g * 4);
    ushort4 r;
    r.x = f2bf_rne(v.x * nr);
    r.y = f2bf_rne(v.y * nr);
    r.z = f2bf_rne(v.z * nr);
    r.w = f2bf_rne(v.w * nr);
    *reinterpret_cast<ushort4*>(hn + (size_t)g * 4) = r;
  }
}

// ---------------- layer-1 pull (bf16 gather): aggB[n] = bf16(sum hn[s]) ----------------
__global__ __launch_bounds__(256) void k_pull1(
    const uint16_t* __restrict__ hn, const int* __restrict__ rowptr,
    const int* __restrict__ esrc, uint16_t* __restrict__ aggB, int N) {
  int node = blockIdx.x * 8 + (threadIdx.x >> 5);
  if (node >= N) return;
  int lane = threadIdx.x & 31;
  int lo = rowptr[node], hi = rowptr[node + 1];
  float4 a0 = {0,0,0,0}, a1 = {0,0,0,0}, a2 = {0,0,0,0}, a3 = {0,0,0,0};
  int e = lo;
  for (; e + 7 < hi; e += 8) {
    int s0 = esrc[e],     s1 = esrc[e + 1], s2 = esrc[e + 2], s3 = esrc[e + 3];
    int s4 = esrc[e + 4], s5 = esrc[e + 5], s6 = esrc[e + 6], s7 = esrc[e + 7];
    uint2 v0 = *reinterpret_cast<const uint2*>(hn + (size_t)s0 * N_IN + lane * 4);
    uint2 v1 = *reinterpret_cast<const uint2*>(hn + (size_t)s1 * N_IN + lane * 4);
    uint2 v2 = *reinterpret_cast<const uint2*>(hn + (size_t)s2 * N_IN + lane * 4);
    uint2 v3 = *reinterpret_cast<const uint2*>(hn + (size_t)s3 * N_IN + lane * 4);
    uint2 v4 = *reinterpret_cast<const uint2*>(hn + (size_t)s4 * N_IN + lane * 4);
    uint2 v5 = *reinterpret_cast<const uint2*>(hn + (size_t)s5 * N_IN + lane * 4);
    uint2 v6 = *reinterpret_cast<const uint2*>(hn + (size_t)s6 * N_IN + lane * 4);
    uint2 v7 = *reinterpret_cast<const uint2*>(hn + (size_t)s7 * N_IN + lane * 4);
    a0.x += bflo(v0.x); a0.y += bfhi(v0.x); a0.z += bflo(v0.y); a0.w += bfhi(v0.y);
    a1.x += bflo(v1.x); a1.y += bfhi(v1.x); a1.z += bflo(v1.y); a1.w += bfhi(v1.y);
    a2.x += bflo(v2.x); a2.y += bfhi(v2.x); a2.z += bflo(v2.y); a2.w += bfhi(v2.y);
    a3.x += bflo(v3.x); a3.y += bfhi(v3.x); a3.z += bflo(v3.y); a3.w += bfhi(v3.y);
    a0.x += bflo(v4.x); a0.y += bfhi(v4.x); a0.z += bflo(v4.y); a0.w += bfhi(v4.y);
    a1.x += bflo(v5.x); a1.y += bfhi(v5.x); a1.z += bflo(v5.y); a1.w += bfhi(v5.y);
    a2.x += bflo(v6.x); a2.y += bfhi(v6.x); a2.z += bflo(v6.y); a2.w += bfhi(v6.y);
    a3.x += bflo(v7.x); a3.y += bfhi(v7.x); a3.z += bflo(v7.y); a3.w += bfhi(v7.y);
  }
  for (; e < hi; e++) {
    uint2 v0 = *reinterpret_cast<const uint2*>(hn + (size_t)esrc[e] * N_IN + lane * 4);
    a0.x += bflo(v0.x); a0.y += bfhi(v0.x); a0.z += bflo(v0.y); a0.w += bfhi(v0.y);
  }
  float4 r;
  r.x = (a0.x + a1.x) + (a2.x + a3.x);
  r.y = (a0.y + a1.y) + (a2.y + a3.y);
  r.z = (a0.z + a1.z) + (a2.z + a3.z);
  r.w = (a0.w + a1.w) + (a2.w + a3.w);
  ushort4 p = make_ushort4(f2bf_rne(r.x), f2bf_rne(r.y), f2bf_rne(r.z), f2bf_rne(r.w));
  *reinterpret_cast<ushort4*>(aggB + (size_t)node * N_IN + lane * 4) = p;
}

// ---------------- fused GEMM1+GEMM2: h1 tile staged in LDS, never hits global ----------------
// part1: h1 = dropout(relu((aggB@W1)*norm+b1))*norm -> LDS (bf16, XOR-swizzled cols)
// part2: z = h1 @ W2 -> zbf
__global__ __launch_bounds__(256) void k_gemm12(
    const uint16_t* __restrict__ aggB,
    const uint4* __restrict__ W1H, const uint4* __restrict__ W1L,
    const float* __restrict__ b1, const float* __restrict__ norm,
    const uint16_t* __restrict__ mask,
    const uint4* __restrict__ W2H, const uint4* __restrict__ W2L,
    uint16_t* __restrict__ zbf, int Nn) {
  __shared__ uint16_t h1[64 * 256];   // 32 KB; col swizzle: col ^ ((row&7)<<3)
  const int tid = threadIdx.x;
  const int wave = tid >> 6, lane = tid & 63;
  const int row0 = blockIdx.x * 64 + wave * 16;
  const int lrow = lane & 15, lk = lane >> 4;
  int arow = row0 + lrow; if (arow >= Nn) arow = Nn - 1;

  // ---- part 1: 64x256 = aggB[64x128] @ W1[128x256]
  f32x4 acc[16];
#pragma unroll
  for (int c = 0; c < 16; c++) acc[c] = f32x4{0.f, 0.f, 0.f, 0.f};
#pragma unroll
  for (int ks = 0; ks < 4; ks++) {
    union { uint4 q; bf16x8 v; } ah;
    ah.q = *reinterpret_cast<const uint4*>(aggB + (size_t)arow * N_IN + ks * 32 + lk * 8);
#pragma unroll
    for (int c = 0; c < 16; c++) {
      union { uint4 q; bf16x8 v; } bh, bl;
      bh.q = W1H[(c * 4 + ks) * 64 + lane];
      bl.q = W1L[(c * 4 + ks) * 64 + lane];
      acc[c] = __builtin_amdgcn_mfma_f32_16x16x32_bf16(ah.v, bh.v, acc[c], 0, 0, 0);
      acc[c] = __builtin_amdgcn_mfma_f32_16x16x32_bf16(ah.v, bl.v, acc[c], 0, 0, 0);
    }
  }

  // ---- epilogue into LDS (rows >= Nn: norm=0 & mask=0 -> exact 0)
  const int colb = lane & 15, rgrp = lane >> 4;
#pragma unroll
  for (int r = 0; r < 4; r++) {
    int lrw = wave * 16 + rgrp * 4 + r;
    int row = blockIdx.x * 64 + lrw;
    float nr = (row < Nn) ? norm[row] : 0.f;
    uint32_t m = (row < Nn) ? (uint32_t)mask[row * 16 + colb] : 0u;
    int sw = (lrw & 7) << 3;
#pragma unroll
    for (int c = 0; c < 16; c++) {
      int col = c * 16 + colb;
      float v = fmaf(acc[c][r], nr, b1[col]);
      v = fmaxf(v, 0.f);
      v = ((m >> c) & 1u) ? v * (2.0f * nr) : 0.f;
      h1[lrw * 256 + (col ^ sw)] = f2bf_rne(v);
    }
  }
  __syncthreads();

  // ---- part 2: z[64x64] = h1[64x256] @ W2[256x64]
  f32x4 acc2[4];
#pragma unroll
  for (int c = 0; c < 4; c++) acc2[c] = f32x4{0.f, 0.f, 0.f, 0.f};
  const int myrow = wave * 16 + lrow;
  const int sw2 = (myrow & 7) << 3;
#pragma unroll
  for (int ks = 0; ks < 8; ks++) {
    union { uint4 q; bf16x8 v; } ah;
    int c0 = (ks * 32 + lk * 8) ^ sw2;   // 8-aligned group, swizzle preserves contiguity
    ah.q = *reinterpret_cast<const uint4*>(&h1[myrow * 256 + c0]);
#pragma unroll
    for (int c = 0; c < 4; c++) {
      union { uint4 q; bf16x8 v; } bh, bl;
      bh.q = W2H[(c * 8 + ks) * 64 + lane];
      bl.q = W2L[(c * 8 + ks) * 64 + lane];
      acc2[c] = __builtin_amdgcn_mfma_f32_16x16x32_bf16(ah.v, bh.v, acc2[c], 0, 0, 0);
      acc2[c] = __builtin_amdgcn_mfma_f32_16x16x32_bf16(ah.v, bl.v, acc2[c], 0, 0, 0);
    }
  }
#pragma unroll
  for (int r = 0; r < 4; r++) {
    int row = row0 + rgrp * 4 + r;
    if (row >= Nn) continue;
#pragma unroll
    for (int c = 0; c < 4; c++)
      zbf[(size_t)row * N_OUT + c * 16 + colb] = f2bf_rne(acc2[c][r]);
  }
}

// ---------------- layer-2 pull (bf16 gather) fused epilogue ----------------
__global__ __launch_bounds__(256) void k_pull2(
    const uint16_t* __restrict__ zbf, const float* __restrict__ norm,
    const float* __restrict__ b2, const int* __restrict__ rowptr,
    const int* __restrict__ esrc, float* __restrict__ out, int N) {
  int node = blockIdx.x * 16 + (threadIdx.x >> 4);
  if (node >= N) return;
  int lane = threadIdx.x & 15;
  int lo = rowptr[node], hi = rowptr[node + 1];
  float4 a0 = {0,0,0,0}, a1 = {0,0,0,0}, a2 = {0,0,0,0}, a3 = {0,0,0,0};
  int e = lo;
  for (; e + 7 < hi; e += 8) {
    int s0 = esrc[e],     s1 = esrc[e + 1], s2 = esrc[e + 2], s3 = esrc[e + 3];
    int s4 = esrc[e + 4], s5 = esrc[e + 5], s6 = esrc[e + 6], s7 = esrc[e + 7];
    uint2 v0 = *reinterpret_cast<const uint2*>(zbf + (size_t)s0 * N_OUT + lane * 4);
    uint2 v1 = *reinterpret_cast<const uint2*>(zbf + (size_t)s1 * N_OUT + lane * 4);
    uint2 v2 = *reinterpret_cast<const uint2*>(zbf + (size_t)s2 * N_OUT + lane * 4);
    uint2 v3 = *reinterpret_cast<const uint2*>(zbf + (size_t)s3 * N_OUT + lane * 4);
    uint2 v4 = *reinterpret_cast<const uint2*>(zbf + (size_t)s4 * N_OUT + lane * 4);
    uint2 v5 = *reinterpret_cast<const uint2*>(zbf + (size_t)s5 * N_OUT + lane * 4);
    uint2 v6 = *reinterpret_cast<const uint2*>(zbf + (size_t)s6 * N_OUT + lane * 4);
    uint2 v7 = *reinterpret_cast<const uint2*>(zbf + (size_t)s7 * N_OUT + lane * 4);
    a0.x += bflo(v0.x); a0.y += bfhi(v0.x); a0.z += bflo(v0.y); a0.w += bfhi(v0.y);
    a1.x += bflo(v1.x); a1.y += bfhi(v1.x); a1.z += bflo(v1.y); a1.w += bfhi(v1.y);
    a2.x += bflo(v2.x); a2.y += bfhi(v2.x); a2.z += bflo(v2.y); a2.w += bfhi(v2.y);
    a3.x += bflo(v3.x); a3.y += bfhi(v3.x); a3.z += bflo(v3.y); a3.w += bfhi(v3.y);
    a0.x += bflo(v4.x); a0.y += bfhi(v4.x); a0.z += bflo(v4.y); a0.w += bfhi(v4.y);
    a1.x += bflo(v5.x); a1.y += bfhi(v5.x); a1.z += bflo(v5.y); a1.w += bfhi(v5.y);
    a2.x += bflo(v6.x); a2.y += bfhi(v6.x); a2.z += bflo(v6.y); a2.w += bfhi(v6.y);
    a3.x += bflo(v7.x); a3.y += bfhi(v7.x); a3.z += bflo(v7.y); a3.w += bfhi(v7.y);
  }
  for (; e < hi; e++) {
    uint2 v0 = *reinterpret_cast<const uint2*>(zbf + (size_t)esrc[e] * N_OUT + lane * 4);
    a0.x += bflo(v0.x); a0.y += bfhi(v0.x); a0.z += bflo(v0.y); a0.w += bfhi(v0.y);
  }
  float nn = norm[node];
  float4 bb = *reinterpret_cast<const float4*>(b2 + lane * 4);
  float4 r;
  r.x = ((a0.x + a1.x) + (a2.x + a3.x)) * nn + bb.x;
  r.y = ((a0.y + a1.y) + (a2.y + a3.y)) * nn + bb.y;
  r.z = ((a0.z + a1.z) + (a2.z + a3.z)) * nn + bb.z;
  r.w = ((a0.w + a1.w) + (a2.w + a3.w)) * nn + bb.w;
  *reinterpret_cast<float4*>(out + (size_t)node * N_OUT + lane * 4) = r;
}

extern "C" void kernel_launch(void* const* d_in, const int* in_sizes, int n_in,
                              void* d_out, int out_size, void* d_ws, size_t ws_size,
                              hipStream_t stream) {
  const float* h  = (const float*)d_in[0];
  const float* W1 = (const float*)d_in[1];
  const float* b1 = (const float*)d_in[2];
  const float* W2 = (const float*)d_in[3];
  const float* b2 = (const float*)d_in[4];
  const int* eidx = (const int*)d_in[5];
  const int N = in_sizes[0] / N_IN;
  const int E = in_sizes[5] / 2;
  const int NBE = (E + CHK - 1) / CHK;
  const int NBM = (N * 16 + 255) / 256;
  const int NS  = (N + 3) / 4;
  const int NH  = (N * 32 + 255) / 256;

  char* ws = (char*)d_ws;
  size_t off = 0;
  auto alloc = [&](size_t bytes) { void* p = ws + off; off += (bytes + 511) & ~(size_t)511; return p; };
  int*      rowptr = (int*)alloc((size_t)(N + 1) * 4);
  float*    norm   = (float*)alloc((size_t)N * 4);
  int*      esrc   = (int*)alloc((size_t)E * 4);
  int*      bktCur = (int*)alloc((size_t)256 * 4);
  uint16_t* mask   = (uint16_t*)alloc((size_t)N * 16 * 2);
  uint4*    W1H    = (uint4*)alloc((size_t)16 * 4 * 64 * 16);
  uint4*    W1L    = (uint4*)alloc((size_t)16 * 4 * 64 * 16);
  uint4*    W2H    = (uint4*)alloc((size_t)4 * 8 * 64 * 16);
  uint4*    W2L    = (uint4*)alloc((size_t)4 * 8 * 64 * 16);
  uint2*    eb     = (uint2*)alloc((size_t)256 * CAP * 8);     // 12.6 MB
  uint16_t* hn     = (uint16_t*)alloc((size_t)N * N_IN * 2);   // 12.8 MB
  uint16_t* aggB   = (uint16_t*)alloc((size_t)N * N_IN * 2);   // 12.8 MB
  uint16_t* zbf    = (uint16_t*)alloc((size_t)N * N_OUT * 2);  // 6.4 MB (no alias: fused kernel)
  float*    out    = (float*)d_out;

  // 1. zero bucket cursors
  hipMemsetAsync(bktCur, 0, 256 * 4, stream);

  // 2. fused front: edge scatter || dropout mask || W packs
  k_front<<<NBE + NBM + 16 + 8, 256, 0, stream>>>(eidx, E, bktCur, eb,
                                                  mask, N, W1, W1H, W1L, W2, W2H, W2L, NBE);

  // 3. per-bucket CSR build
  k_bucket_csr<<<256, 256, 0, stream>>>(eb, bktCur, rowptr, norm, esrc, N, E);

  // 4. fused mid: row sort || bf16 gather plane
  k_mid<<<NS + NH, 256, 0, stream>>>(esrc, rowptr, N, h, norm, hn, NS);

  // 5. layer-1 aggregation
  k_pull1<<<(N + 7) / 8, 256, 0, stream>>>(hn, rowptr, esrc, aggB, N);

  // 6. fused GEMM1+GEMM2 (h1 never leaves LDS)
  k_gemm12<<<(N + 63) / 64, 256, 0, stream>>>(aggB, W1H, W1L, b1, norm, mask,
                                              W2H, W2L, zbf, N);

  // 7. layer-2 aggregation + epilogue
  k_pull2<<<(N + 15) / 16, 256, 0, stream>>>(zbf, norm, b2, rowptr, esrc, out, N);
}

// Round 14
// 145.851 us; speedup vs baseline: 1.1284x; 1.1284x over previous
//
#include <hip/hip_runtime.h>
#include <stdint.h>

#define N_IN  128
#define N_H   256
#define N_OUT 64
#define CHK   2048   // edges per scatter block
#define CAP   6144   // fixed bucket capacity (mean 4096, sigma ~64 -> 32-sigma margin)

typedef __attribute__((ext_vector_type(8))) __bf16 bf16x8;
typedef __attribute__((ext_vector_type(4))) float f32x4;

// ---------------- Threefry-2x32 (JAX-compatible) ----------------
__device__ __forceinline__ void tf4(uint32_t& x0, uint32_t& x1,
                                    const int r0, const int r1, const int r2, const int r3) {
  x0 += x1; x1 = (x1 << r0) | (x1 >> (32 - r0)); x1 ^= x0;
  x0 += x1; x1 = (x1 << r1) | (x1 >> (32 - r1)); x1 ^= x0;
  x0 += x1; x1 = (x1 << r2) | (x1 >> (32 - r2)); x1 ^= x0;
  x0 += x1; x1 = (x1 << r3) | (x1 >> (32 - r3)); x1 ^= x0;
}

__device__ __forceinline__ uint2 threefry2x32(uint32_t k0, uint32_t k1, uint32_t x0, uint32_t x1) {
  const uint32_t k2 = k0 ^ k1 ^ 0x1BD11BDAu;
  x0 += k0; x1 += k1;
  tf4(x0, x1, 13, 15, 26, 6);   x0 += k1; x1 += k2 + 1u;
  tf4(x0, x1, 17, 29, 16, 24);  x0 += k2; x1 += k0 + 2u;
  tf4(x0, x1, 13, 15, 26, 6);   x0 += k0; x1 += k1 + 3u;
  tf4(x0, x1, 17, 29, 16, 24);  x0 += k1; x1 += k2 + 4u;
  tf4(x0, x1, 13, 15, 26, 6);   x0 += k2; x1 += k0 + 5u;
  return make_uint2(x0, x1);
}

// f32 -> bf16 round-to-nearest-even
__device__ __forceinline__ uint16_t f2bf_rne(float v) {
  uint32_t b = __builtin_bit_cast(uint32_t, v);
  b += 0x7fffu + ((b >> 16) & 1u);
  return (uint16_t)(b >> 16);
}
__device__ __forceinline__ float bflo(uint32_t w) { return __builtin_bit_cast(float, w << 16); }
__device__ __forceinline__ float bfhi(uint32_t w) { return __builtin_bit_cast(float, w & 0xffff0000u); }

// ---------------- W fragment packing body ----------------
__device__ __forceinline__ void packW_body(const float* __restrict__ W,
                                           uint4* __restrict__ WH, uint4* __restrict__ WL,
                                           int Ncols, int nct, int nks, int g) {
  if (g >= nct * nks * 64) return;
  int lane = g & 63;
  int grp = g >> 6;
  int ks = grp % nks, ct = grp / nks;
  int k0 = ks * 32 + (lane >> 4) * 8;
  int col = ct * 16 + (lane & 15);
  uint32_t hb[8], lb[8];
#pragma unroll
  for (int j = 0; j < 8; j++) {
    float w = W[(size_t)(k0 + j) * Ncols + col];
    uint32_t bits = __builtin_bit_cast(uint32_t, w);
    uint32_t hi = bits & 0xffff0000u;
    float lo = w - __builtin_bit_cast(float, hi);
    hb[j] = hi >> 16;
    lb[j] = __builtin_bit_cast(uint32_t, lo) >> 16;
  }
  WH[g] = make_uint4(hb[0] | (hb[1] << 16), hb[2] | (hb[3] << 16),
                     hb[4] | (hb[5] << 16), hb[6] | (hb[7] << 16));
  WL[g] = make_uint4(lb[0] | (lb[1] << 16), lb[2] | (lb[3] << 16),
                     lb[4] | (lb[5] << 16), lb[6] | (lb[7] << 16));
}

// ---------------- k_front: fused [edge scatter | dropout mask | W packs] ----------------
__global__ __launch_bounds__(256) void k_front(
    const int* __restrict__ eidx, int E, int* __restrict__ bktCur, uint2* __restrict__ eb,
    uint16_t* __restrict__ mask, int N,
    const float* __restrict__ W1, uint4* __restrict__ W1H, uint4* __restrict__ W1L,
    const float* __restrict__ W2, uint4* __restrict__ W2H, uint4* __restrict__ W2L,
    int NBE) {
  const int b = blockIdx.x, t = threadIdx.x;
  if (b < NBE) {
    __shared__ int s_nz;
    __shared__ int hist[256];
    __shared__ int base[256];
    if (t == 0) s_nz = 0;
    hist[t] = 0;
    __syncthreads();
    int n = E < 2048 ? E : 2048;
    int nz = 0;
    for (int i = t; i < n; i += 256) nz |= (eidx[2 * i + 1] != 0) ? 1 : 0;
    if (nz) atomicAdd(&s_nz, 1);
    __syncthreads();
    int stride = (s_nz == 0) ? 2 : 1;

    int cb = b * CHK;
    int dc[8], sc[8];
#pragma unroll
    for (int i = 0; i < 8; i++) {
      int e = cb + i * 256 + t;
      if (e < E) {
        dc[i] = eidx[(size_t)(E + e) * stride];
        sc[i] = eidx[(size_t)e * stride];
        atomicAdd(&hist[dc[i] >> 8], 1);
      } else dc[i] = -1;
    }
    __syncthreads();
    int hcnt = hist[t];
    if (hcnt) base[t] = atomicAdd(&bktCur[t], hcnt);
    __syncthreads();
    hist[t] = 0;
    __syncthreads();
#pragma unroll
    for (int i = 0; i < 8; i++) {
      if (dc[i] >= 0) {
        int bk = dc[i] >> 8;
        int r = atomicAdd(&hist[bk], 1);
        eb[(size_t)bk * CAP + base[bk] + r] = make_uint2((unsigned)sc[i], (unsigned)dc[i]);
      }
    }
  } else {
    const int NBM = (N * 16 + 255) >> 8;
    int bb = b - NBE;
    if (bb < NBM) {
      int g = bb * 256 + t;
      if (g >= N * 16) return;
      uint32_t row = (uint32_t)(g >> 4), colb = (uint32_t)(g & 15);
      uint32_t bse = row * 256u + colb;
      uint32_t m = 0;
#pragma unroll
      for (int ct = 0; ct < 16; ct++) {
        uint2 o = threefry2x32(0u, 42u, 0u, bse + (uint32_t)ct * 16u);
        uint32_t bits = o.x ^ o.y;
        m |= ((~bits) >> 31) << ct;
      }
      mask[g] = (uint16_t)m;
    } else if (bb < NBM + 16) {
      packW_body(W1, W1H, W1L, N_H, 16, 4, (bb - NBM) * 256 + t);
    } else {
      packW_body(W2, W2H, W2L, N_OUT, 4, 8, (bb - NBM - 16) * 256 + t);
    }
  }
}

// ---------------- per-bucket CSR build ----------------
__global__ __launch_bounds__(256) void k_bucket_csr(
    const uint2* __restrict__ eb, const int* __restrict__ bktCur,
    int* __restrict__ rowptr, float* __restrict__ norm,
    int* __restrict__ esrc, int N, int E) {
  __shared__ int s[256];
  __shared__ int cnt[256];
  __shared__ int pfx[256];
  __shared__ int cur[256];
  const int b = blockIdx.x, t = threadIdx.x;
  if (b == 0 && t == 0) rowptr[N] = E;
  if (b * 256 >= N) return;
  int xc = bktCur[t];
  s[t] = xc;
  __syncthreads();
  for (int off = 1; off < 256; off <<= 1) {
    int u = (t >= off) ? s[t - off] : 0;
    __syncthreads();
    s[t] += u;
    __syncthreads();
  }
  const int lo = (b > 0) ? s[b - 1] : 0;
  const int ecnt = s[b] - lo;
  const uint2* ebb = eb + (size_t)b * CAP;
  cnt[t] = 0;
  __syncthreads();
  for (int e = t; e < ecnt; e += 256)
    atomicAdd(&cnt[ebb[e].y & 255u], 1);
  __syncthreads();
  int x = cnt[t];
  pfx[t] = x;
  __syncthreads();
  for (int off = 1; off < 256; off <<= 1) {
    int u = (t >= off) ? pfx[t - off] : 0;
    __syncthreads();
    pfx[t] += u;
    __syncthreads();
  }
  int excl = pfx[t] - x;
  int node = b * 256 + t;
  if (node < N) {
    rowptr[node] = lo + excl;
    norm[node] = x > 0 ? rsqrtf((float)x) : 1.0f;
  }
  cur[t] = excl;
  __syncthreads();
  for (int e = t; e < ecnt; e += 256) {
    uint2 r = ebb[e];
    int d = (int)(r.y & 255u);
    int p = atomicAdd(&cur[d], 1);
    esrc[lo + p] = (int)r.x;
  }
}

// ---------------- k_mid: fused [bitonic row sort | hn = bf16(h*norm) plane] ----------------
__global__ __launch_bounds__(256) void k_mid(
    int* __restrict__ esrc, const int* __restrict__ rowptr, int N,
    const float* __restrict__ h, const float* __restrict__ norm,
    uint16_t* __restrict__ hn, int NS) {
  const int b = blockIdx.x, t = threadIdx.x;
  if (b < NS) {
    int node = b * 4 + (t >> 6);
    if (node >= N) return;
    const int lane = t & 63;
    int lo = rowptr[node], hi = rowptr[node + 1], d = hi - lo;
    if (d <= 1) return;
    if (d <= 64) {
      int v = (lane < d) ? esrc[lo + lane] : 0x7fffffff;
#pragma unroll
      for (int k = 2; k <= 64; k <<= 1) {
#pragma unroll
        for (int j = k >> 1; j > 0; j >>= 1) {
          int other = __shfl_xor(v, j);
          bool up = ((lane & k) == 0);
          bool lower = ((lane & j) == 0);
          int mn = min(v, other), mx = max(v, other);
          v = (up == lower) ? mn : mx;
        }
      }
      if (lane < d) esrc[lo + lane] = v;
    } else if (lane == 0) {
      for (int i = lo + 1; i < hi; i++) {
        int v = esrc[i];
        int j = i - 1;
        while (j >= lo && esrc[j] > v) { esrc[j + 1] = esrc[j]; j--; }
        esrc[j + 1] = v;
      }
    }
  } else {
    int g = (b - NS) * 256 + t;
    if (g >= N * 32) return;
    float nr = norm[g >> 5];
    float4 v = *reinterpret_cast<const float4*>(h + (size_t)g * 4);
    ushort4 r;
    r.x = f2bf_rne(v.x * nr);
    r.y = f2bf_rne(v.y * nr);
    r.z = f2bf_rne(v.z * nr);
    r.w = f2bf_rne(v.w * nr);
    *reinterpret_cast<ushort4*>(hn + (size_t)g * 4) = r;
  }
}

// ---------------- layer-1 pull (bf16 gather): aggB[n] = bf16(sum hn[s]) ----------------
__global__ __launch_bounds__(256) void k_pull1(
    const uint16_t* __restrict__ hn, const int* __restrict__ rowptr,
    const int* __restrict__ esrc, uint16_t* __restrict__ aggB, int N) {
  int node = blockIdx.x * 8 + (threadIdx.x >> 5);
  if (node >= N) return;
  int lane = threadIdx.x & 31;
  int lo = rowptr[node], hi = rowptr[node + 1];
  float4 a0 = {0,0,0,0}, a1 = {0,0,0,0}, a2 = {0,0,0,0}, a3 = {0,0,0,0};
  int e = lo;
  for (; e + 7 < hi; e += 8) {
    int s0 = esrc[e],     s1 = esrc[e + 1], s2 = esrc[e + 2], s3 = esrc[e + 3];
    int s4 = esrc[e + 4], s5 = esrc[e + 5], s6 = esrc[e + 6], s7 = esrc[e + 7];
    uint2 v0 = *reinterpret_cast<const uint2*>(hn + (size_t)s0 * N_IN + lane * 4);
    uint2 v1 = *reinterpret_cast<const uint2*>(hn + (size_t)s1 * N_IN + lane * 4);
    uint2 v2 = *reinterpret_cast<const uint2*>(hn + (size_t)s2 * N_IN + lane * 4);
    uint2 v3 = *reinterpret_cast<const uint2*>(hn + (size_t)s3 * N_IN + lane * 4);
    uint2 v4 = *reinterpret_cast<const uint2*>(hn + (size_t)s4 * N_IN + lane * 4);
    uint2 v5 = *reinterpret_cast<const uint2*>(hn + (size_t)s5 * N_IN + lane * 4);
    uint2 v6 = *reinterpret_cast<const uint2*>(hn + (size_t)s6 * N_IN + lane * 4);
    uint2 v7 = *reinterpret_cast<const uint2*>(hn + (size_t)s7 * N_IN + lane * 4);
    a0.x += bflo(v0.x); a0.y += bfhi(v0.x); a0.z += bflo(v0.y); a0.w += bfhi(v0.y);
    a1.x += bflo(v1.x); a1.y += bfhi(v1.x); a1.z += bflo(v1.y); a1.w += bfhi(v1.y);
    a2.x += bflo(v2.x); a2.y += bfhi(v2.x); a2.z += bflo(v2.y); a2.w += bfhi(v2.y);
    a3.x += bflo(v3.x); a3.y += bfhi(v3.x); a3.z += bflo(v3.y); a3.w += bfhi(v3.y);
    a0.x += bflo(v4.x); a0.y += bfhi(v4.x); a0.z += bflo(v4.y); a0.w += bfhi(v4.y);
    a1.x += bflo(v5.x); a1.y += bfhi(v5.x); a1.z += bflo(v5.y); a1.w += bfhi(v5.y);
    a2.x += bflo(v6.x); a2.y += bfhi(v6.x); a2.z += bflo(v6.y); a2.w += bfhi(v6.y);
    a3.x += bflo(v7.x); a3.y += bfhi(v7.x); a3.z += bflo(v7.y); a3.w += bfhi(v7.y);
  }
  for (; e < hi; e++) {
    uint2 v0 = *reinterpret_cast<const uint2*>(hn + (size_t)esrc[e] * N_IN + lane * 4);
    a0.x += bflo(v0.x); a0.y += bfhi(v0.x); a0.z += bflo(v0.y); a0.w += bfhi(v0.y);
  }
  float4 r;
  r.x = (a0.x + a1.x) + (a2.x + a3.x);
  r.y = (a0.y + a1.y) + (a2.y + a3.y);
  r.z = (a0.z + a1.z) + (a2.z + a3.z);
  r.w = (a0.w + a1.w) + (a2.w + a3.w);
  ushort4 p = make_ushort4(f2bf_rne(r.x), f2bf_rne(r.y), f2bf_rne(r.z), f2bf_rne(r.w));
  *reinterpret_cast<ushort4*>(aggB + (size_t)node * N_IN + lane * 4) = p;
}

// ---------------- fused GEMM1+GEMM2 with W staged in LDS ----------------
// part1: h1 = dropout(relu((aggB@W1)*norm+b1))*norm -> LDS (bf16, XOR-swizzled cols)
// part2: z = h1 @ W2 -> zbf.  W fragments read from global ONCE per block into LDS.
__global__ __launch_bounds__(256) void k_gemm12(
    const uint16_t* __restrict__ aggB,
    const uint4* __restrict__ W1H, const uint4* __restrict__ W1L,
    const float* __restrict__ b1, const float* __restrict__ norm,
    const uint16_t* __restrict__ mask,
    const uint4* __restrict__ W2H, const uint4* __restrict__ W2L,
    uint16_t* __restrict__ zbf, int Nn) {
  __shared__ uint16_t h1[64 * 256];   // 32 KB; col swizzle: col ^ ((row&7)<<3)
  __shared__ uint4 wlds[2048];        // 32 KB W staging (H in [0,1024), L in [1024,2048))
  const int tid = threadIdx.x;
  const int wave = tid >> 6, lane = tid & 63;
  const int row0 = blockIdx.x * 64 + wave * 16;
  const int lrow = lane & 15, lk = lane >> 4;
  int arow = row0 + lrow; if (arow >= Nn) arow = Nn - 1;

  // prefetch the full A row (4 ks fragments, 16 VGPRs)
  uint4 aq[4];
#pragma unroll
  for (int ks = 0; ks < 4; ks++)
    aq[ks] = *reinterpret_cast<const uint4*>(aggB + (size_t)arow * N_IN + ks * 32 + lk * 8);

  // ---- part 1: 64x256 = aggB[64x128] @ W1[128x256], W slice per ks in LDS
  f32x4 acc[16];
#pragma unroll
  for (int c = 0; c < 16; c++) acc[c] = f32x4{0.f, 0.f, 0.f, 0.f};

  for (int ks = 0; ks < 4; ks++) {
    __syncthreads();   // protect wlds from previous iteration's readers
#pragma unroll
    for (int i = 0; i < 4; i++) {
      int g = tid + i * 256;                       // 0..1023: c = g>>6, lane' = g&63
      int src = ((g >> 6) * 4 + ks) * 64 + (g & 63);
      wlds[g]        = W1H[src];
      wlds[1024 + g] = W1L[src];
    }
    __syncthreads();
    union { uint4 q; bf16x8 v; } ah; ah.q = aq[ks];
#pragma unroll
    for (int c = 0; c < 16; c++) {
      union { uint4 q; bf16x8 v; } bh, bl;
      bh.q = wlds[c * 64 + lane];
      bl.q = wlds[1024 + c * 64 + lane];
      acc[c] = __builtin_amdgcn_mfma_f32_16x16x32_bf16(ah.v, bh.v, acc[c], 0, 0, 0);
      acc[c] = __builtin_amdgcn_mfma_f32_16x16x32_bf16(ah.v, bl.v, acc[c], 0, 0, 0);
    }
  }

  // ---- epilogue into LDS (rows >= Nn: norm=0 & mask=0 -> exact 0)
  const int colb = lane & 15, rgrp = lane >> 4;
#pragma unroll
  for (int r = 0; r < 4; r++) {
    int lrw = wave * 16 + rgrp * 4 + r;
    int row = blockIdx.x * 64 + lrw;
    float nr = (row < Nn) ? norm[row] : 0.f;
    uint32_t m = (row < Nn) ? (uint32_t)mask[row * 16 + colb] : 0u;
    int sw = (lrw & 7) << 3;
#pragma unroll
    for (int c = 0; c < 16; c++) {
      int col = c * 16 + colb;
      float v = fmaf(acc[c][r], nr, b1[col]);
      v = fmaxf(v, 0.f);
      v = ((m >> c) & 1u) ? v * (2.0f * nr) : 0.f;
      h1[lrw * 256 + (col ^ sw)] = f2bf_rne(v);
    }
  }

  // ---- part 2: z[64x64] = h1[64x256] @ W2[256x64], W2 in LDS (2 halves of 4 ks)
  f32x4 acc2[4];
#pragma unroll
  for (int c = 0; c < 4; c++) acc2[c] = f32x4{0.f, 0.f, 0.f, 0.f};
  const int myrow = wave * 16 + lrow;
  const int sw2 = (myrow & 7) << 3;

  for (int half = 0; half < 2; half++) {
    __syncthreads();   // protect wlds (and order h1 writes before first read)
#pragma unroll
    for (int i = 0; i < 4; i++) {
      int g = tid + i * 256;                       // 0..1023: c = g>>8, ksl = (g>>6)&3
      int src = ((g >> 8) * 8 + half * 4 + ((g >> 6) & 3)) * 64 + (g & 63);
      wlds[g]        = W2H[src];
      wlds[1024 + g] = W2L[src];
    }
    __syncthreads();
#pragma unroll
    for (int ksl = 0; ksl < 4; ksl++) {
      int ks = half * 4 + ksl;
      union { uint4 q; bf16x8 v; } ah;
      int c0 = (ks * 32 + lk * 8) ^ sw2;           // 8-aligned group, swizzle keeps contiguity
      ah.q = *reinterpret_cast<const uint4*>(&h1[myrow * 256 + c0]);
#pragma unroll
      for (int c = 0; c < 4; c++) {
        union { uint4 q; bf16x8 v; } bh, bl;
        bh.q = wlds[(c * 4 + ksl) * 64 + lane];
        bl.q = wlds[1024 + (c * 4 + ksl) * 64 + lane];
        acc2[c] = __builtin_amdgcn_mfma_f32_16x16x32_bf16(ah.v, bh.v, acc2[c], 0, 0, 0);
        acc2[c] = __builtin_amdgcn_mfma_f32_16x16x32_bf16(ah.v, bl.v, acc2[c], 0, 0, 0);
      }
    }
  }
#pragma unroll
  for (int r = 0; r < 4; r++) {
    int row = row0 + rgrp * 4 + r;
    if (row >= Nn) continue;
#pragma unroll
    for (int c = 0; c < 4; c++)
      zbf[(size_t)row * N_OUT + c * 16 + colb] = f2bf_rne(acc2[c][r]);
  }
}

// ---------------- layer-2 pull (bf16 gather) fused epilogue ----------------
__global__ __launch_bounds__(256) void k_pull2(
    const uint16_t* __restrict__ zbf, const float* __restrict__ norm,
    const float* __restrict__ b2, const int* __restrict__ rowptr,
    const int* __restrict__ esrc, float* __restrict__ out, int N) {
  int node = blockIdx.x * 16 + (threadIdx.x >> 4);
  if (node >= N) return;
  int lane = threadIdx.x & 15;
  int lo = rowptr[node], hi = rowptr[node + 1];
  float4 a0 = {0,0,0,0}, a1 = {0,0,0,0}, a2 = {0,0,0,0}, a3 = {0,0,0,0};
  int e = lo;
  for (; e + 7 < hi; e += 8) {
    int s0 = esrc[e],     s1 = esrc[e + 1], s2 = esrc[e + 2], s3 = esrc[e + 3];
    int s4 = esrc[e + 4], s5 = esrc[e + 5], s6 = esrc[e + 6], s7 = esrc[e + 7];
    uint2 v0 = *reinterpret_cast<const uint2*>(zbf + (size_t)s0 * N_OUT + lane * 4);
    uint2 v1 = *reinterpret_cast<const uint2*>(zbf + (size_t)s1 * N_OUT + lane * 4);
    uint2 v2 = *reinterpret_cast<const uint2*>(zbf + (size_t)s2 * N_OUT + lane * 4);
    uint2 v3 = *reinterpret_cast<const uint2*>(zbf + (size_t)s3 * N_OUT + lane * 4);
    uint2 v4 = *reinterpret_cast<const uint2*>(zbf + (size_t)s4 * N_OUT + lane * 4);
    uint2 v5 = *reinterpret_cast<const uint2*>(zbf + (size_t)s5 * N_OUT + lane * 4);
    uint2 v6 = *reinterpret_cast<const uint2*>(zbf + (size_t)s6 * N_OUT + lane * 4);
    uint2 v7 = *reinterpret_cast<const uint2*>(zbf + (size_t)s7 * N_OUT + lane * 4);
    a0.x += bflo(v0.x); a0.y += bfhi(v0.x); a0.z += bflo(v0.y); a0.w += bfhi(v0.y);
    a1.x += bflo(v1.x); a1.y += bfhi(v1.x); a1.z += bflo(v1.y); a1.w += bfhi(v1.y);
    a2.x += bflo(v2.x); a2.y += bfhi(v2.x); a2.z += bflo(v2.y); a2.w += bfhi(v2.y);
    a3.x += bflo(v3.x); a3.y += bfhi(v3.x); a3.z += bflo(v3.y); a3.w += bfhi(v3.y);
    a0.x += bflo(v4.x); a0.y += bfhi(v4.x); a0.z += bflo(v4.y); a0.w += bfhi(v4.y);
    a1.x += bflo(v5.x); a1.y += bfhi(v5.x); a1.z += bflo(v5.y); a1.w += bfhi(v5.y);
    a2.x += bflo(v6.x); a2.y += bfhi(v6.x); a2.z += bflo(v6.y); a2.w += bfhi(v6.y);
    a3.x += bflo(v7.x); a3.y += bfhi(v7.x); a3.z += bflo(v7.y); a3.w += bfhi(v7.y);
  }
  for (; e < hi; e++) {
    uint2 v0 = *reinterpret_cast<const uint2*>(zbf + (size_t)esrc[e] * N_OUT + lane * 4);
    a0.x += bflo(v0.x); a0.y += bfhi(v0.x); a0.z += bflo(v0.y); a0.w += bfhi(v0.y);
  }
  float nn = norm[node];
  float4 bb = *reinterpret_cast<const float4*>(b2 + lane * 4);
  float4 r;
  r.x = ((a0.x + a1.x) + (a2.x + a3.x)) * nn + bb.x;
  r.y = ((a0.y + a1.y) + (a2.y + a3.y)) * nn + bb.y;
  r.z = ((a0.z + a1.z) + (a2.z + a3.z)) * nn + bb.z;
  r.w = ((a0.w + a1.w) + (a2.w + a3.w)) * nn + bb.w;
  *reinterpret_cast<float4*>(out + (size_t)node * N_OUT + lane * 4) = r;
}

extern "C" void kernel_launch(void* const* d_in, const int* in_sizes, int n_in,
                              void* d_out, int out_size, void* d_ws, size_t ws_size,
                              hipStream_t stream) {
  const float* h  = (const float*)d_in[0];
  const float* W1 = (const float*)d_in[1];
  const float* b1 = (const float*)d_in[2];
  const float* W2 = (const float*)d_in[3];
  const float* b2 = (const float*)d_in[4];
  const int* eidx = (const int*)d_in[5];
  const int N = in_sizes[0] / N_IN;
  const int E = in_sizes[5] / 2;
  const int NBE = (E + CHK - 1) / CHK;
  const int NBM = (N * 16 + 255) / 256;
  const int NS  = (N + 3) / 4;
  const int NH  = (N * 32 + 255) / 256;

  char* ws = (char*)d_ws;
  size_t off = 0;
  auto alloc = [&](size_t bytes) { void* p = ws + off; off += (bytes + 511) & ~(size_t)511; return p; };
  int*      rowptr = (int*)alloc((size_t)(N + 1) * 4);
  float*    norm   = (float*)alloc((size_t)N * 4);
  int*      esrc   = (int*)alloc((size_t)E * 4);
  int*      bktCur = (int*)alloc((size_t)256 * 4);
  uint16_t* mask   = (uint16_t*)alloc((size_t)N * 16 * 2);
  uint4*    W1H    = (uint4*)alloc((size_t)16 * 4 * 64 * 16);
  uint4*    W1L    = (uint4*)alloc((size_t)16 * 4 * 64 * 16);
  uint4*    W2H    = (uint4*)alloc((size_t)4 * 8 * 64 * 16);
  uint4*    W2L    = (uint4*)alloc((size_t)4 * 8 * 64 * 16);
  uint2*    eb     = (uint2*)alloc((size_t)256 * CAP * 8);     // 12.6 MB
  uint16_t* hn     = (uint16_t*)alloc((size_t)N * N_IN * 2);   // 12.8 MB
  uint16_t* aggB   = (uint16_t*)alloc((size_t)N * N_IN * 2);   // 12.8 MB
  uint16_t* zbf    = (uint16_t*)alloc((size_t)N * N_OUT * 2);  // 6.4 MB
  float*    out    = (float*)d_out;

  // 1. zero bucket cursors
  hipMemsetAsync(bktCur, 0, 256 * 4, stream);

  // 2. fused front: edge scatter || dropout mask || W packs
  k_front<<<NBE + NBM + 16 + 8, 256, 0, stream>>>(eidx, E, bktCur, eb,
                                                  mask, N, W1, W1H, W1L, W2, W2H, W2L, NBE);

  // 3. per-bucket CSR build
  k_bucket_csr<<<256, 256, 0, stream>>>(eb, bktCur, rowptr, norm, esrc, N, E);

  // 4. fused mid: row sort || bf16 gather plane
  k_mid<<<NS + NH, 256, 0, stream>>>(esrc, rowptr, N, h, norm, hn, NS);

  // 5. layer-1 aggregation
  k_pull1<<<(N + 7) / 8, 256, 0, stream>>>(hn, rowptr, esrc, aggB, N);

  // 6. fused GEMM1+GEMM2 (W staged in LDS, h1 never leaves LDS)
  k_gemm12<<<(N + 63) / 64, 256, 0, stream>>>(aggB, W1H, W1L, b1, norm, mask,
                                              W2H, W2L, zbf, N);

  // 7. layer-2 aggregation + epilogue
  k_pull2<<<(N + 15) / 16, 256, 0, stream>>>(zbf, norm, b2, rowptr, esrc, out, N);
}